// Round 15
// baseline (17.386 us; speedup 1.0000x reference)
//
#include <hip/hip_runtime.h>
#include <hip/hip_bf16.h>

typedef short short8 __attribute__((ext_vector_type(8)));
typedef float f32x4 __attribute__((ext_vector_type(4)));

// RNE f32->bf16 via hardware v_cvt_pk_bf16_f32 (HIP intrinsic, compiler-scheduled)
static __device__ __forceinline__ ushort2 pk2(float a, float b) {
    __hip_bfloat162 h = __float22bfloat162_rn(make_float2(a, b));
    ushort2 r;
    __builtin_memcpy(&r, &h, 4);
    return r;
}
static __device__ __forceinline__ unsigned short bf1(float a) {
    __hip_bfloat16 h = __float2bfloat16(a);
    unsigned short r;
    __builtin_memcpy(&r, &h, 2);
    return r;
}

// R14 structure (16.2us) with the A-staging barrier chain de-serialized:
//  - mean-row eliminated algebraically: pooled = sum_{n<15} (bit*rc + rc/15)*inj_n
//    (bit15 always set; inj15 = mean@We = (1/15)*sum inj_n) -> folded into the
//    mask fragment as two bf16 weights rcA=rc*16/15, rcB=rc/15.
//  - E rows loaded per-lane directly from global (L2) -> no E LDS, so the inj
//    MFMA phase runs BEFORE the barrier and the A-tile HBM loads (issued first,
//    held in regs) drain under it. A is cvt+written to LDS after inj; the one
//    barrier then only covers fast LDS writes.
__global__ __launch_bounds__(256)
void fused_all(const float* __restrict__ patches,
               const float* __restrict__ embs,
               const int* __restrict__ locations,
               const float* __restrict__ Wp,
               const float* __restrict__ We,
               float* __restrict__ out) {
    __shared__ __align__(16) unsigned short Ash[64 * 256];    // 32 KB, swizzled
    __shared__ unsigned maskL[64];
    __shared__ float rcL[64];

    const int bid = blockIdx.x, t = threadIdx.x;
    const int b = bid >> 6, pt = (bid >> 2) & 15, ct = bid & 3;
    const int p0 = pt * 64, c0 = ct * 64;
    const int wv = t >> 6, lane = t & 63, lhi = lane >> 4, llo = lane & 15;
    const int oc = c0 + wv * 16 + llo;   // output column this lane owns

    // ---- 1. issue A-tile loads (HBM, longest latency), hold in registers ----
    const float* pbase = patches + (size_t)(b * 1024 + p0) * 256;
    float4 areg[16];
    #pragma unroll
    for (int it = 0; it < 16; ++it) {
        int u = t + it * 256;
        int row = u >> 6, c4 = u & 63;
        areg[it] = *reinterpret_cast<const float4*>(pbase + row * 256 + c4 * 4);
    }

    // ---- 2. masks + 1/cnt for the 64 pixels ----
    if (t < 64) {
        int p = p0 + t;
        int h = p >> 5, w = p & 31;
        const int* loc = locations + b * 60;
        unsigned m = 1u << 15;  // full-image box always contains
        #pragma unroll
        for (int nb = 0; nb < 15; ++nb) {
            int y0 = loc[nb * 4 + 0] & ~1;
            int x0 = loc[nb * 4 + 1] & ~1;
            int y1 = (loc[nb * 4 + 2] & ~1) + 2;
            int x1 = (loc[nb * 4 + 3] & ~1) + 2;
            if (h >= y0 && h < y1 && w >= x0 && w < x1) m |= 1u << nb;
        }
        maskL[t] = m;
        rcL[t] = 1.0f / (float)__popc(m);
    }

    // ---- 3. inj slice via MFMA; E row per-lane direct from global (L2) ----
    // lane(llo,*) supplies E_ext row llo; row 15 (mean) eliminated -> zeros.
    const float* erow = embs + (size_t)(b * 15 + (llo < 15 ? llo : 0)) * 256;
    const bool ez = (llo == 15);
    f32x4 accI = (f32x4){0.f, 0.f, 0.f, 0.f};
    #pragma unroll
    for (int ks = 0; ks < 8; ++ks) {
        float4 e0 = *reinterpret_cast<const float4*>(erow + ks * 32 + lhi * 8);
        float4 e1 = *reinterpret_cast<const float4*>(erow + ks * 32 + lhi * 8 + 4);
        ushort2 pa = pk2(e0.x, e0.y), pb = pk2(e0.z, e0.w);
        ushort2 pc = pk2(e1.x, e1.y), pd = pk2(e1.z, e1.w);
        short8 afr;
        afr[0] = ez ? 0 : (short)pa.x; afr[1] = ez ? 0 : (short)pa.y;
        afr[2] = ez ? 0 : (short)pb.x; afr[3] = ez ? 0 : (short)pb.y;
        afr[4] = ez ? 0 : (short)pc.x; afr[5] = ez ? 0 : (short)pc.y;
        afr[6] = ez ? 0 : (short)pd.x; afr[7] = ez ? 0 : (short)pd.y;
        short8 bfr;
        #pragma unroll
        for (int rr = 0; rr < 4; ++rr) {
            float w0 = We[(size_t)(ks * 32 + lhi * 8 + 2 * rr + 0) * 256 + oc];
            float w1 = We[(size_t)(ks * 32 + lhi * 8 + 2 * rr + 1) * 256 + oc];
            ushort2 p2 = pk2(w0, w1);
            bfr[2 * rr + 0] = (short)p2.x;
            bfr[2 * rr + 1] = (short)p2.y;
        }
        accI = __builtin_amdgcn_mfma_f32_16x16x32_bf16(afr, bfr, accI, 0, 0, 0);
    }
    // inj C-layout -> jf B-fragment via intra-wave bpermute (lhi>=2 wraps ->
    // finite garbage, masked by mfrag=0 for k>=16)
    short8 jf;
    {
        ushort2 plo = pk2(accI[0], accI[1]);
        ushort2 phi = pk2(accI[2], accI[3]);
        int q0 = (int)((unsigned)plo.x | ((unsigned)plo.y << 16));
        int q1 = (int)((unsigned)phi.x | ((unsigned)phi.y << 16));
        int a0 = (llo + 32 * lhi) << 2;
        union { short8 s; int i[4]; } J;
        J.i[0] = __builtin_amdgcn_ds_bpermute(a0, q0);
        J.i[1] = __builtin_amdgcn_ds_bpermute(a0, q1);
        J.i[2] = __builtin_amdgcn_ds_bpermute(a0 + 64, q0);
        J.i[3] = __builtin_amdgcn_ds_bpermute(a0 + 64, q1);
        jf = J.s;
    }

    // ---- 4. convert + write A tile to swizzled LDS (loads long since landed) ----
    #pragma unroll
    for (int it = 0; it < 16; ++it) {
        int u = t + it * 256;
        int row = u >> 6, c4 = u & 63;
        float4 f = areg[it];
        ushort2 lo = pk2(f.x, f.y), hi = pk2(f.z, f.w);
        ushort4 o = {lo.x, lo.y, hi.x, hi.y};
        int byte = row * 512 + ((c4 * 8) ^ ((row & 7) << 4));
        *reinterpret_cast<ushort4*>(reinterpret_cast<char*>(Ash) + byte) = o;
    }
    __syncthreads();   // the ONLY block barrier (A regs already drained)

    // ---- 5. main GEMM: 4 pixel-groups x 8 k-steps; B gathered from Wp (L2) ----
    f32x4 acc[4];
    #pragma unroll
    for (int mt = 0; mt < 4; ++mt) acc[mt] = (f32x4){0.f, 0.f, 0.f, 0.f};
    #pragma unroll
    for (int ks = 0; ks < 8; ++ks) {
        short8 bfr;
        #pragma unroll
        for (int rr = 0; rr < 4; ++rr) {
            float w0 = Wp[(size_t)(ks * 32 + lhi * 8 + 2 * rr + 0) * 256 + oc];
            float w1 = Wp[(size_t)(ks * 32 + lhi * 8 + 2 * rr + 1) * 256 + oc];
            ushort2 p2 = pk2(w0, w1);
            bfr[2 * rr + 0] = (short)p2.x;
            bfr[2 * rr + 1] = (short)p2.y;
        }
        #pragma unroll
        for (int mt = 0; mt < 4; ++mt) {
            int row = mt * 16 + llo;
            const short8 af = *reinterpret_cast<const short8*>(
                reinterpret_cast<const char*>(Ash)
                + row * 512 + (((ks * 32 + lhi * 8) * 2) ^ ((row & 7) << 4)));
            acc[mt] = __builtin_amdgcn_mfma_f32_16x16x32_bf16(af, bfr, acc[mt], 0, 0, 0);
        }
    }

    // ---- 6. epilogue: mean-folded mask MFMA (rcA = rc*16/15 if masked,
    //         rcB = rc/15 if not, k<15 only), then store ----
    #pragma unroll
    for (int mt = 0; mt < 4; ++mt) {
        unsigned m = maskL[mt * 16 + llo];
        float rc = rcL[mt * 16 + llo];
        unsigned short rcA = bf1(rc * (16.0f / 15.0f));
        unsigned short rcB = bf1(rc * (1.0f / 15.0f));
        short8 mfrag;
        #pragma unroll
        for (int r = 0; r < 8; ++r) {
            int k = lhi * 8 + r;
            mfrag[r] = (k < 15) ? (short)(((m >> k) & 1u) ? rcA : rcB) : (short)0;
        }
        f32x4 accE = __builtin_amdgcn_mfma_f32_16x16x32_bf16(
            mfrag, jf, (f32x4){0.f, 0.f, 0.f, 0.f}, 0, 0, 0);
        float* ob = out + (size_t)(b * 1024 + p0 + mt * 16) * 256;
        #pragma unroll
        for (int j = 0; j < 4; ++j)
            ob[(lhi * 4 + j) * 256 + oc] = acc[mt][j] + accE[j];
    }
}

extern "C" void kernel_launch(void* const* d_in, const int* in_sizes, int n_in,
                              void* d_out, int out_size, void* d_ws, size_t ws_size,
                              hipStream_t stream) {
    const float* patches = (const float*)d_in[0];
    const float* embs    = (const float*)d_in[1];
    const int*   locs    = (const int*)d_in[2];
    const float* Wp      = (const float*)d_in[3];
    const float* We      = (const float*)d_in[4];
    float* out = (float*)d_out;

    fused_all<<<512, 256, 0, stream>>>(patches, embs, locs, Wp, We, out);
}

// Round 16
// 16.211 us; speedup vs baseline: 1.0725x; 1.0725x over previous
//
#include <hip/hip_runtime.h>
#include <hip/hip_bf16.h>

typedef short short8 __attribute__((ext_vector_type(8)));
typedef float f32x4 __attribute__((ext_vector_type(4)));

// RNE f32->bf16 via hardware v_cvt_pk_bf16_f32 (HIP intrinsic, compiler-scheduled)
static __device__ __forceinline__ ushort2 pk2(float a, float b) {
    __hip_bfloat162 h = __float22bfloat162_rn(make_float2(a, b));
    ushort2 r;
    __builtin_memcpy(&r, &h, 4);
    return r;
}
static __device__ __forceinline__ unsigned short bf1(float a) {
    __hip_bfloat16 h = __float2bfloat16(a);
    unsigned short r;
    __builtin_memcpy(&r, &h, 2);
    return r;
}

// R14 structure (best: 16.19us) + algebraic mean-row elimination (verified R15):
//   pooled = sum_{n<15} (bit_n*rc + rc/15) * inj_n   (bit15 always set, and
//   inj_15 = mean(E)@We = (1/15) sum_{n<15} inj_n), folded into the mask
//   fragment as rcA = rc*16/15 (masked) / rcB = rc/15 (unmasked). E row 15 in
//   LDS is zeroed; the 15-read mean-reduction pass is deleted.
// Block = (b, 64-px, 64-col), 4 waves; ONE __syncthreads; no workspace;
// inj->jf via intra-wave ds_bpermute (no fence; lhi>=2 garbage masked by 0).
__global__ __launch_bounds__(256)
void fused_all(const float* __restrict__ patches,
               const float* __restrict__ embs,
               const int* __restrict__ locations,
               const float* __restrict__ Wp,
               const float* __restrict__ We,
               float* __restrict__ out) {
    __shared__ __align__(16) unsigned short Ash[64 * 256];    // 32 KB, swizzled
    __shared__ __align__(16) unsigned short Ebf[16 * 256];    // 8 KB, swizzled
    __shared__ unsigned maskL[64];
    __shared__ float rcL[64];

    const int bid = blockIdx.x, t = threadIdx.x;
    const int b = bid >> 6, pt = (bid >> 2) & 15, ct = bid & 3;
    const int p0 = pt * 64, c0 = ct * 64;
    const int wv = t >> 6, lane = t & 63, lhi = lane >> 4, llo = lane & 15;
    const int oc = c0 + wv * 16 + llo;   // output column this lane owns

    // ---- A staging: patches[b, p0..p0+64, :] -> bf16 LDS, XOR-swizzled rows ----
    const float* pbase = patches + (size_t)(b * 1024 + p0) * 256;
    #pragma unroll
    for (int it = 0; it < 16; ++it) {
        int u = t + it * 256;
        int row = u >> 6, c4 = u & 63;
        float4 f = *reinterpret_cast<const float4*>(pbase + row * 256 + c4 * 4);
        ushort2 lo = pk2(f.x, f.y), hi = pk2(f.z, f.w);
        ushort4 o = {lo.x, lo.y, hi.x, hi.y};
        int byte = row * 512 + ((c4 * 8) ^ ((row & 7) << 4));
        *reinterpret_cast<ushort4*>(reinterpret_cast<char*>(Ash) + byte) = o;
    }

    // ---- E staging: rows 0..14 bf16 swizzled; row 15 zeroed (mean eliminated) ----
    if (t < 128) {
        const int c0e = t * 2;
        #pragma unroll
        for (int r = 0; r < 15; ++r) {
            float2 v = *reinterpret_cast<const float2*>(embs + (size_t)(b * 15 + r) * 256 + c0e);
            ushort2 p2 = pk2(v.x, v.y);
            unsigned pk = (unsigned)p2.x | ((unsigned)p2.y << 16);
            *reinterpret_cast<unsigned*>(reinterpret_cast<char*>(Ebf)
                + r * 512 + ((c0e * 2) ^ ((r & 7) << 4))) = pk;
        }
        *reinterpret_cast<unsigned*>(reinterpret_cast<char*>(Ebf)
            + 15 * 512 + ((c0e * 2) ^ (7 << 4))) = 0u;
    }

    // ---- masks + 1/cnt for the 64 pixels ----
    if (t < 64) {
        int p = p0 + t;
        int h = p >> 5, w = p & 31;
        const int* loc = locations + b * 60;
        unsigned m = 1u << 15;  // full-image box always contains
        #pragma unroll
        for (int nb = 0; nb < 15; ++nb) {
            int y0 = loc[nb * 4 + 0] & ~1;
            int x0 = loc[nb * 4 + 1] & ~1;
            int y1 = (loc[nb * 4 + 2] & ~1) + 2;
            int x1 = (loc[nb * 4 + 3] & ~1) + 2;
            if (h >= y0 && h < y1 && w >= x0 && w < x1) m |= 1u << nb;
        }
        maskL[t] = m;
        rcL[t] = 1.0f / (float)__popc(m);
    }
    __syncthreads();   // the ONLY block barrier

    // ---- inj slice: (E @ We)[:, oc] via MFMA (rows 0..14; row 15 = 0) ----
    f32x4 accI = (f32x4){0.f, 0.f, 0.f, 0.f};
    #pragma unroll
    for (int ks = 0; ks < 8; ++ks) {
        const short8 afr = *reinterpret_cast<const short8*>(
            reinterpret_cast<const char*>(Ebf)
            + llo * 512 + ((ks * 64 + lhi * 16) ^ ((llo & 7) << 4)));
        short8 bfr;
        #pragma unroll
        for (int rr = 0; rr < 4; ++rr) {
            float w0 = We[(size_t)(ks * 32 + lhi * 8 + 2 * rr + 0) * 256 + oc];
            float w1 = We[(size_t)(ks * 32 + lhi * 8 + 2 * rr + 1) * 256 + oc];
            ushort2 p2 = pk2(w0, w1);
            bfr[2 * rr + 0] = (short)p2.x;
            bfr[2 * rr + 1] = (short)p2.y;
        }
        accI = __builtin_amdgcn_mfma_f32_16x16x32_bf16(afr, bfr, accI, 0, 0, 0);
    }
    // inj C-layout -> jf B-fragment via intra-wave bpermute (no LDS, no fence);
    // lhi>=2 wraps -> finite garbage, masked by mfrag=0.
    short8 jf;
    {
        ushort2 plo = pk2(accI[0], accI[1]);
        ushort2 phi = pk2(accI[2], accI[3]);
        int q0 = (int)((unsigned)plo.x | ((unsigned)plo.y << 16));
        int q1 = (int)((unsigned)phi.x | ((unsigned)phi.y << 16));
        int a0 = (llo + 32 * lhi) << 2;
        union { short8 s; int i[4]; } J;
        J.i[0] = __builtin_amdgcn_ds_bpermute(a0, q0);
        J.i[1] = __builtin_amdgcn_ds_bpermute(a0, q1);
        J.i[2] = __builtin_amdgcn_ds_bpermute(a0 + 64, q0);
        J.i[3] = __builtin_amdgcn_ds_bpermute(a0 + 64, q1);
        jf = J.s;
    }

    // ---- main GEMM: 4 pixel-groups x 8 k-steps; B gathered from Wp (L2) ----
    f32x4 acc[4];
    #pragma unroll
    for (int mt = 0; mt < 4; ++mt) acc[mt] = (f32x4){0.f, 0.f, 0.f, 0.f};
    #pragma unroll
    for (int ks = 0; ks < 8; ++ks) {
        short8 bfr;
        #pragma unroll
        for (int rr = 0; rr < 4; ++rr) {
            float w0 = Wp[(size_t)(ks * 32 + lhi * 8 + 2 * rr + 0) * 256 + oc];
            float w1 = Wp[(size_t)(ks * 32 + lhi * 8 + 2 * rr + 1) * 256 + oc];
            ushort2 p2 = pk2(w0, w1);
            bfr[2 * rr + 0] = (short)p2.x;
            bfr[2 * rr + 1] = (short)p2.y;
        }
        #pragma unroll
        for (int mt = 0; mt < 4; ++mt) {
            int row = mt * 16 + llo;
            const short8 af = *reinterpret_cast<const short8*>(
                reinterpret_cast<const char*>(Ash)
                + row * 512 + (((ks * 32 + lhi * 8) * 2) ^ ((row & 7) << 4)));
            acc[mt] = __builtin_amdgcn_mfma_f32_16x16x32_bf16(af, bfr, acc[mt], 0, 0, 0);
        }
    }

    // ---- epilogue: mean-folded mask MFMA (rcA if masked, rcB if not; k<15) ----
    #pragma unroll
    for (int mt = 0; mt < 4; ++mt) {
        unsigned m = maskL[mt * 16 + llo];
        float rc = rcL[mt * 16 + llo];
        unsigned short rcA = bf1(rc * (16.0f / 15.0f));
        unsigned short rcB = bf1(rc * (1.0f / 15.0f));
        short8 mfrag;
        #pragma unroll
        for (int r = 0; r < 8; ++r) {
            int k = lhi * 8 + r;
            mfrag[r] = (k < 15) ? (short)(((m >> k) & 1u) ? rcA : rcB) : (short)0;
        }
        f32x4 accE = __builtin_amdgcn_mfma_f32_16x16x32_bf16(
            mfrag, jf, (f32x4){0.f, 0.f, 0.f, 0.f}, 0, 0, 0);
        float* ob = out + (size_t)(b * 1024 + p0 + mt * 16) * 256;
        #pragma unroll
        for (int j = 0; j < 4; ++j)
            ob[(lhi * 4 + j) * 256 + oc] = acc[mt][j] + accE[j];
    }
}

extern "C" void kernel_launch(void* const* d_in, const int* in_sizes, int n_in,
                              void* d_out, int out_size, void* d_ws, size_t ws_size,
                              hipStream_t stream) {
    const float* patches = (const float*)d_in[0];
    const float* embs    = (const float*)d_in[1];
    const int*   locs    = (const int*)d_in[2];
    const float* Wp      = (const float*)d_in[3];
    const float* We      = (const float*)d_in[4];
    float* out = (float*)d_out;

    fused_all<<<512, 256, 0, stream>>>(patches, embs, locs, Wp, We, out);
}